// Round 21
// baseline (206.663 us; speedup 1.0000x reference)
//
#include <hip/hip_runtime.h>

typedef __attribute__((ext_vector_type(8))) _Float16 f16x8;
typedef __attribute__((ext_vector_type(4))) float f32x4;

static constexpr int TT = 100, BB = 256, DD = 784, HH = 256;
static constexpr int MM = TT * BB;      // 25600
static constexpr int K1PAD = 832;       // 784 -> 13*64
static constexpr int N2PAD = 800;       // 784 -> 25*32 (W2 row pad)
static constexpr float MIDSC = 2048.0f, INVMID = 1.0f / 2048.0f;

__device__ __forceinline__ unsigned short f2h(float x) {
  _Float16 h = (_Float16)x;
  return *(unsigned short*)&h;
}
__device__ __forceinline__ float h2f(unsigned short u) {
  _Float16 h = *(_Float16*)&u;
  return (float)h;
}
__device__ __forceinline__ void glds16(const void* g, void* l) {
  __builtin_amdgcn_global_load_lds(
      (const __attribute__((address_space(1))) unsigned int*)g,
      (__attribute__((address_space(3))) unsigned int*)l, 16, 0, 0);
}

// Split fp32 W[N][K] into 2 f16 planes [Npad][Kpad]:
//   p0 = f16(w), p1 = f16((w - p0) * 2048); reconstruct p0 + p1/2048 (~2^-22 rel).
__global__ __launch_bounds__(256)
void split_w(const float* __restrict__ W, unsigned short* __restrict__ Ws,
             int N, int K, int Npad, int Kpad) {
  int idx = blockIdx.x * 256 + threadIdx.x;
  int total = Npad * Kpad;
  if (idx >= total) return;
  int row = idx / Kpad, col = idx - row * Kpad;
  float w = (row < N && col < K) ? W[row * K + col] : 0.0f;
  unsigned short h0 = f2h(w);
  float r = (w - h2f(h0)) * MIDSC;
  Ws[idx] = h0;
  Ws[total + idx] = f2h(r);
}

// Layer-1 GEMM v7 (BK=64): cur1[M,256] = X[M,784] @ (2-plane f16 W1)^T + b1.
// Rationale: across r12/r16/r17 the per-block-K-step cost is ~2200-2800 cy
// REGARDLESS of work inside; time ~ blocks x steps. BK=64 halves steps (25->13)
// at the same 400-block 128^2 tile: 64 MFMA/wave/step.
//   A: 2-buf padded LDS [128][72] (pad -> conflict-free frag reads, no XOR),
//      reg-staged fp32->f16 (r12 pattern, 8 float4/thread).
//   B: 2-buf linear LDS [2][128][64], glds with XOR-in-source swizzle
//      (phys_chunk = log_chunk ^ (row&7), 8 chunks/row of 128B).
// Waits (queue never exceeds 40 <= 63 HW cap): packA(kb+1)'s implicit register
// wait drains A(kb+1) and (FIFO) B(kb); explicit vmcnt(8) drains B(kb+1)
// (L2-hot W1s, flight ~= compute phase) keeping A(kb+2) (HBM) flying a full step.
// launch_bounds(256,1): 1 block/CU (LDS 100 KB), no VGPR cap -> NO SPILL.
// Per-acc MFMA k-order unchanged; pad chunks add exact +0.0 -> cur1 bitwise
// identical to r12/r14/r20.
__global__ __launch_bounds__(256, 1)
void gemm1(const float* __restrict__ X, const unsigned short* __restrict__ Bs,
           const float* __restrict__ bias, float* __restrict__ C) {
  constexpr int Kpad = K1PAD, nkb = Kpad / 64;   // 13
  constexpr int AST = 72;                        // A LDS row stride (ushorts)
  __shared__ unsigned short Asm[2][128 * AST];     // 36 KB
  __shared__ unsigned short Bsm[2][2][128 * 64];   // 64 KB
  const int tid = threadIdx.x;
  const int bm = blockIdx.x * 128, bn = blockIdx.y * 128;
  const int wid = tid >> 6, lane = tid & 63;
  const int wr = (wid >> 1) * 64, wc = (wid & 1) * 64;
  const int l15 = lane & 15, l4 = lane >> 4;

  f32x4 acc[2][4][4];
#pragma unroll
  for (int s = 0; s < 2; ++s)
#pragma unroll
    for (int m = 0; m < 4; ++m)
#pragma unroll
      for (int n = 0; n < 4; ++n) acc[s][m][n] = (f32x4){0.f, 0.f, 0.f, 0.f};

  // B glds: wave = (plane gp, 64-row half gr); 8 glds of 8 rows each.
  // Lane -> row = rowbase + (lane>>3), phys chunk = lane&7; source octet
  // pre-swizzled: (lane&7) ^ ((lane>>3)&7)  [rowbase is a multiple of 8].
  const int gp = wid >> 1, gr = (wid & 1) * 64;
  const size_t pstr = (size_t)HH * Kpad;
  const unsigned short* bsrc = Bs + (size_t)gp * pstr
      + (size_t)(bn + gr + (lane >> 3)) * Kpad
      + ((lane & 7) ^ ((lane >> 3) & 7)) * 8;

  // A staging: thread -> row = tid&127, col half = (tid>>7)*32; 4 chunks of 8.
  const int r0 = tid & 127;
  const int cb = (tid >> 7) * 32;

  float4 aA[8], aB[8];

  auto loadA = [&](int kb, float4 (&d)[8]) {
    const float* xr = &X[(size_t)(bm + r0) * DD];
#pragma unroll
    for (int c = 0; c < 4; ++c) {
      const int col = kb * 64 + cb + c * 8;
      if (col < DD) {                  // 784 % 8 == 0: whole octet in/out
        d[2 * c]     = *(const float4*)(xr + col);
        d[2 * c + 1] = *(const float4*)(xr + col + 4);
      } else {
        d[2 * c] = make_float4(0.f, 0.f, 0.f, 0.f);
        d[2 * c + 1] = d[2 * c];
      }
    }
  };
  auto packA = [&](int bi, const float4 (&s_)[8]) {
    const unsigned ONE = 0x3C00u;
    auto pk = [&](float a, float b) {
      return (a != 0.f ? ONE : 0u) | (b != 0.f ? (ONE << 16) : 0u);
    };
#pragma unroll
    for (int c = 0; c < 4; ++c) {
      uint4 v;
      v.x = pk(s_[2 * c].x, s_[2 * c].y);
      v.y = pk(s_[2 * c].z, s_[2 * c].w);
      v.z = pk(s_[2 * c + 1].x, s_[2 * c + 1].y);
      v.w = pk(s_[2 * c + 1].z, s_[2 * c + 1].w);
      *(uint4*)&Asm[bi][r0 * AST + cb + c * 8] = v;
    }
  };
  auto stageB = [&](int t) {
    const int bi = t & 1;
    const unsigned short* src = bsrc + t * 64;
#pragma unroll
    for (int i = 0; i < 8; ++i)
      glds16(src + (size_t)i * 8 * Kpad, &Bsm[bi][gp][(gr + i * 8) * 64]);
  };
  auto compute = [&](int kb) {
    const int bi = kb & 1;
#pragma unroll
    for (int ks = 0; ks < 2; ++ks) {   // two K=32 sub-chunks, ascending k
      f16x8 afr[4];
#pragma unroll
      for (int m = 0; m < 4; ++m)
        afr[m] = *(const f16x8*)&Asm[bi][(wr + m * 16 + l15) * AST + ks * 32 + l4 * 8];
#pragma unroll
      for (int s = 0; s < 2; ++s) {
        f16x8 bfr[4];
#pragma unroll
        for (int n = 0; n < 4; ++n)
          bfr[n] = *(const f16x8*)&Bsm[bi][s][(wc + n * 16 + l15) * 64
                    + ((ks * 4 + l4) ^ (l15 & 7)) * 8];
#pragma unroll
        for (int m = 0; m < 4; ++m)
#pragma unroll
          for (int n = 0; n < 4; ++n)
            acc[s][m][n] = __builtin_amdgcn_mfma_f32_16x16x32_f16(afr[m], bfr[n], acc[s][m][n], 0, 0, 0);
      }
    }
  };
  auto stepK = [&](int kb, const float4 (&pk_)[8], float4 (&ld_)[8]) {
    if (kb + 1 < nkb) packA((kb + 1) & 1, pk_);  // implicit: drains A(kb+1), B(kb)
    if (kb + 1 < nkb) stageB(kb + 1);            // +32
    if (kb + 2 < nkb) loadA(kb + 2, ld_);        // +8 (after B: stays in flight)
    compute(kb);
    __builtin_amdgcn_sched_barrier(0);
    // queue: [B(kb+1):32, A(kb+2):8] -> drain B, keep A flying a full step
    if (kb + 2 < nkb)      asm volatile("s_waitcnt vmcnt(8)" ::: "memory");
    else                   asm volatile("s_waitcnt vmcnt(0)" ::: "memory");
    asm volatile("s_waitcnt lgkmcnt(0)" ::: "memory");
    __builtin_amdgcn_sched_barrier(0);
    __builtin_amdgcn_s_barrier();
    __builtin_amdgcn_sched_barrier(0);
  };

  // prologue: A0 (8), B0 (32); drain A0 (vmcnt 32); pack A0; A1; drain B0 (vmcnt 8)
  loadA(0, aA);
  stageB(0);
  asm volatile("s_waitcnt vmcnt(32)" ::: "memory");
  packA(0, aA);
  loadA(1, aB);
  asm volatile("s_waitcnt vmcnt(8)" ::: "memory");
  asm volatile("s_waitcnt lgkmcnt(0)" ::: "memory");
  __builtin_amdgcn_s_barrier();
  __builtin_amdgcn_sched_barrier(0);

  for (int kb2 = 0; kb2 < nkb; kb2 += 2) {
    stepK(kb2, aB, aA);
    if (kb2 + 1 < nkb) stepK(kb2 + 1, aA, aB);
  }

#pragma unroll
  for (int m = 0; m < 4; ++m)
#pragma unroll
    for (int n = 0; n < 4; ++n) {
      const int col = bn + wc + n * 16 + l15;
      const float bv = bias[col];
#pragma unroll
      for (int r = 0; r < 4; ++r) {
        const int row = bm + wr + m * 16 + l4 * 4 + r;
        C[(size_t)row * HH + col] = fmaf(acc[1][m][n][r], INVMID, acc[0][m][n][r]) + bv;
      }
    }
}

// fp32 currents -> f16 spikes, 4 elems/thread
__global__ __launch_bounds__(256)
void lif_scan_h4(const float4* __restrict__ cur, uint2* __restrict__ spk,
                 int NE4, int nt) {
  const int tid = blockIdx.x * 256 + threadIdx.x;
  float4 mem = make_float4(0.f, 0.f, 0.f, 0.f);
  auto step1 = [](float& m, float c) {
    const float reset = (m > 1.0f) ? 1.0f : 0.0f;
    m = __fsub_rn(__fadd_rn(__fmul_rn(0.9f, m), c), reset);
    return (m > 1.0f);
  };
#pragma unroll 4
  for (int t = 0; t < nt; ++t) {
    const float4 c = cur[(size_t)t * NE4 + tid];
    unsigned s0 = step1(mem.x, c.x) ? 0x3C00u : 0u;
    unsigned s1 = step1(mem.y, c.y) ? 0x3C00u : 0u;
    unsigned s2 = step1(mem.z, c.z) ? 0x3C00u : 0u;
    unsigned s3 = step1(mem.w, c.w) ? 0x3C00u : 0u;
    uint2 o;
    o.x = s0 | (s1 << 16);
    o.y = s2 | (s3 << 16);
    spk[(size_t)t * NE4 + tid] = o;
  }
}

// Fused layer-2 GEMM + LIF v8 (r14 verbatim): single-wave blocks, zero barriers,
// 2-t software pipeline, counted vmcnt; stores never drained mid-loop.
__global__ __launch_bounds__(64)
void fused_l2(const unsigned short* __restrict__ spk1,   // [100][256][256] f16
              const unsigned short* __restrict__ W2s,    // 2 planes [800][256] f16
              const float* __restrict__ b2, float* __restrict__ out) {
  __shared__ unsigned short Asm[4][16 * 256];   // 32 KB ring
  const int lane = threadIdx.x;                  // 64
  const int l15 = lane & 15, l4 = lane >> 4;
  const int bb = blockIdx.x / 49, dd = blockIdx.x - bb * 49;  // 16 x 49
  const int b0 = bb * 16, d0 = dd * 16;

  const unsigned short* asrc[8];
#pragma unroll
  for (int i = 0; i < 8; ++i) {
    const int r = 2 * i + (lane >> 5);
    const int e = ((lane & 31) * 8) ^ ((r & 7) << 3);
    asrc[i] = spk1 + (size_t)(b0 + r) * HH + e;
  }
  auto stageA = [&](int t) {
    const size_t toff = (size_t)t * (BB * HH);
    unsigned short* dst = &Asm[t & 3][0];
#pragma unroll
    for (int i = 0; i < 8; ++i)
      glds16(asrc[i] + toff, dst + 2 * i * 256);
  };

  stageA(0);
  stageA(1);

  f16x8 wfr[2][8];
  const unsigned short* wb = W2s + (size_t)(d0 + l15) * HH + l4 * 8;
#pragma unroll
  for (int s = 0; s < 2; ++s)
#pragma unroll
    for (int ks = 0; ks < 8; ++ks)
      wfr[s][ks] = *(const f16x8*)(wb + (size_t)s * (N2PAD * HH) + ks * 32);
  const float bv = b2[d0 + l15];

  asm volatile("s_waitcnt vmcnt(0)" ::: "memory");
  __builtin_amdgcn_sched_barrier(0);

  f32x4 mem = (f32x4){0.f, 0.f, 0.f, 0.f};
  float* obase = out + (size_t)(b0 + l4 * 4) * DD + d0 + l15;

  int roff[8];
#pragma unroll
  for (int ks = 0; ks < 8; ++ks)
    roff[ks] = l15 * 256 + ((ks * 32 + l4 * 8) ^ ((l15 & 7) << 3));

  for (int p = 0; p < TT; p += 2) {
    if (p + 2 < TT) { stageA(p + 2); stageA(p + 3); }
    if (p == 0)            asm volatile("s_waitcnt vmcnt(16)" ::: "memory");
    else if (p + 2 < TT)   asm volatile("s_waitcnt vmcnt(24)" ::: "memory");
    else                   asm volatile("s_waitcnt vmcnt(8)"  ::: "memory");
    __builtin_amdgcn_sched_barrier(0);

    const unsigned short* bufA = &Asm[p & 3][0];
    const unsigned short* bufB = &Asm[(p + 1) & 3][0];

    f16x8 rA[8];
#pragma unroll
    for (int ks = 0; ks < 8; ++ks)
      rA[ks] = *(const f16x8*)&bufA[roff[ks]];
    f32x4 p0a = (f32x4){0.f, 0.f, 0.f, 0.f}, p0b = p0a, p1a = p0a, p1b = p0a;
#pragma unroll
    for (int ks = 0; ks < 4; ++ks) {
      p0a = __builtin_amdgcn_mfma_f32_16x16x32_f16(rA[ks], wfr[0][ks], p0a, 0, 0, 0);
      p1a = __builtin_amdgcn_mfma_f32_16x16x32_f16(rA[ks], wfr[1][ks], p1a, 0, 0, 0);
    }
#pragma unroll
    for (int ks = 4; ks < 8; ++ks) {
      p0b = __builtin_amdgcn_mfma_f32_16x16x32_f16(rA[ks], wfr[0][ks], p0b, 0, 0, 0);
      p1b = __builtin_amdgcn_mfma_f32_16x16x32_f16(rA[ks], wfr[1][ks], p1b, 0, 0, 0);
    }

    f16x8 rB[8];
#pragma unroll
    for (int ks = 0; ks < 8; ++ks)
      rB[ks] = *(const f16x8*)&bufB[roff[ks]];

    {
      float* op = obase + (size_t)p * ((size_t)BB * DD);
#pragma unroll
      for (int r = 0; r < 4; ++r) {
        const float p0 = p0a[r] + p0b[r];
        const float p1 = p1a[r] + p1b[r];
        const float cur = fmaf(p1, INVMID, p0) + bv;
        const float reset = (mem[r] > 1.0f) ? 1.0f : 0.0f;
        mem[r] = __fsub_rn(__fadd_rn(__fmul_rn(0.9f, mem[r]), cur), reset);
        op[(size_t)r * DD] = (mem[r] > 1.0f) ? 1.0f : 0.0f;
      }
    }

    f32x4 q0a = (f32x4){0.f, 0.f, 0.f, 0.f}, q0b = q0a, q1a = q0a, q1b = q0a;
#pragma unroll
    for (int ks = 0; ks < 4; ++ks) {
      q0a = __builtin_amdgcn_mfma_f32_16x16x32_f16(rB[ks], wfr[0][ks], q0a, 0, 0, 0);
      q1a = __builtin_amdgcn_mfma_f32_16x16x32_f16(rB[ks], wfr[1][ks], q1a, 0, 0, 0);
    }
#pragma unroll
    for (int ks = 4; ks < 8; ++ks) {
      q0b = __builtin_amdgcn_mfma_f32_16x16x32_f16(rB[ks], wfr[0][ks], q0b, 0, 0, 0);
      q1b = __builtin_amdgcn_mfma_f32_16x16x32_f16(rB[ks], wfr[1][ks], q1b, 0, 0, 0);
    }
    {
      float* op = obase + (size_t)(p + 1) * ((size_t)BB * DD);
#pragma unroll
      for (int r = 0; r < 4; ++r) {
        const float p0 = q0a[r] + q0b[r];
        const float p1 = q1a[r] + q1b[r];
        const float cur = fmaf(p1, INVMID, p0) + bv;
        const float reset = (mem[r] > 1.0f) ? 1.0f : 0.0f;
        mem[r] = __fsub_rn(__fadd_rn(__fmul_rn(0.9f, mem[r]), cur), reset);
        op[(size_t)r * DD] = (mem[r] > 1.0f) ? 1.0f : 0.0f;
      }
    }
  }
}

extern "C" void kernel_launch(void* const* d_in, const int* in_sizes, int n_in,
                              void* d_out, int out_size, void* d_ws, size_t ws_size,
                              hipStream_t stream) {
  const float* x  = (const float*)d_in[0];
  const float* W1 = (const float*)d_in[1];
  const float* b1 = (const float*)d_in[2];
  const float* W2 = (const float*)d_in[3];
  const float* b2 = (const float*)d_in[4];
  float* out = (float*)d_out;

  const size_t w1s_elems = (size_t)2 * HH * K1PAD;    // 425984
  const size_t w2s_elems = (size_t)2 * N2PAD * HH;    // 409600
  unsigned short* W1s = (unsigned short*)d_ws;
  unsigned short* W2s = W1s + w1s_elems;
  float* cur1 = (float*)(W2s + w2s_elems);
  unsigned short* spk1 = (unsigned short*)(cur1 + (size_t)MM * HH);

  dim3 blk(256);

  split_w<<<dim3((HH * K1PAD + 255) / 256), blk, 0, stream>>>(W1, W1s, HH, DD, HH, K1PAD);
  split_w<<<dim3((N2PAD * HH + 255) / 256), blk, 0, stream>>>(W2, W2s, DD, HH, N2PAD, HH);

  // layer 1: cur1[M,256] = X @ W1^T + b1 (400 blocks x 4 waves, BK=64, 13 steps)
  gemm1<<<dim3(MM / 128, HH / 128), blk, 0, stream>>>(x, W1s, b1, cur1);

  // layer 1 LIF -> f16 spikes
  lif_scan_h4<<<dim3((BB * HH / 4) / 256), blk, 0, stream>>>(
      (const float4*)cur1, (uint2*)spk1, BB * HH / 4, TT);

  // layer 2 GEMM + LIF fused: 784 single-wave blocks, zero barriers, 2t pipeline
  fused_l2<<<dim3(16 * 49), dim3(64), 0, stream>>>(spk1, W2s, b2, out);
}

// Round 22
// 174.864 us; speedup vs baseline: 1.1819x; 1.1819x over previous
//
#include <hip/hip_runtime.h>

typedef __attribute__((ext_vector_type(8))) _Float16 f16x8;
typedef __attribute__((ext_vector_type(4))) float f32x4;

static constexpr int TT = 100, BB = 256, DD = 784, HH = 256;
static constexpr int MM = TT * BB;      // 25600
static constexpr int K1PAD = 800;       // 784 -> 25*32
static constexpr int N2PAD = 800;       // 784 -> 25*32 (W2 row pad)
static constexpr float MIDSC = 2048.0f, INVMID = 1.0f / 2048.0f;

__device__ __forceinline__ unsigned short f2h(float x) {
  _Float16 h = (_Float16)x;
  return *(unsigned short*)&h;
}
__device__ __forceinline__ float h2f(unsigned short u) {
  _Float16 h = *(_Float16*)&u;
  return (float)h;
}
__device__ __forceinline__ void glds16(const void* g, void* l) {
  __builtin_amdgcn_global_load_lds(
      (const __attribute__((address_space(1))) unsigned int*)g,
      (__attribute__((address_space(3))) unsigned int*)l, 16, 0, 0);
}

// Split fp32 W[N][K] into 2 f16 planes [Npad][Kpad]:
//   p0 = f16(w), p1 = f16((w - p0) * 2048); reconstruct p0 + p1/2048 (~2^-22 rel).
__global__ __launch_bounds__(256)
void split_w(const float* __restrict__ W, unsigned short* __restrict__ Ws,
             int N, int K, int Npad, int Kpad) {
  int idx = blockIdx.x * 256 + threadIdx.x;
  int total = Npad * Kpad;
  if (idx >= total) return;
  int row = idx / Kpad, col = idx - row * Kpad;
  float w = (row < N && col < K) ? W[row * K + col] : 0.0f;
  unsigned short h0 = f2h(w);
  float r = (w - h2f(h0)) * MIDSC;
  Ws[idx] = h0;
  Ws[total + idx] = f2h(r);
}

// Layer-1 GEMM (r12/r20 config, measured best): cur1[M,256] = X @ W1s^T + b1.
// BM=BN=128, BK=32, 4 waves 2x2, mfma_f32_16x16x32_f16, dual plane accumulators.
__global__ __launch_bounds__(256, 2)
void gemm1(const float* __restrict__ X, const unsigned short* __restrict__ Bs,
           const float* __restrict__ bias, float* __restrict__ C) {
  constexpr int Kpad = K1PAD, nkb = Kpad / 32;   // 25
  __shared__ unsigned short Asm[2][128 * 32];      // 16 KB
  __shared__ unsigned short Bsm[3][2][128 * 32];   // 48 KB
  const int tid = threadIdx.x;
  const int bm = blockIdx.x * 128, bn = blockIdx.y * 128;
  const int wid = tid >> 6, lane = tid & 63;
  const int wr = (wid >> 1) * 64, wc = (wid & 1) * 64;
  const int l15 = lane & 15, l4 = lane >> 4;

  f32x4 acc[2][4][4];
#pragma unroll
  for (int s = 0; s < 2; ++s)
#pragma unroll
    for (int m = 0; m < 4; ++m)
#pragma unroll
      for (int n = 0; n < 4; ++n) acc[s][m][n] = (f32x4){0.f, 0.f, 0.f, 0.f};

  const int rl = wid * 32 + (lane >> 2);
  const int ce = ((lane & 3) ^ ((lane >> 3) & 3)) * 8;
  const size_t pstr = (size_t)HH * Kpad;
  const unsigned short* bsrc0 = Bs + (size_t)(bn + rl) * Kpad + ce;
  const unsigned short* bsrc1 = Bs + (size_t)(bn + rl + 16) * Kpad + ce;

  const int rdsw = (l4 ^ ((l15 >> 1) & 3)) * 8;

  const int r0 = tid >> 2;
  const int c0log = (tid & 3) * 8;
  const int c0phys = ((tid & 3) ^ ((tid >> 3) & 3)) * 8;

  float4 aA[4], aB[4];

  auto loadA = [&](int kb, float4 (&d)[4]) {
    const int col = kb * 32 + c0log;
    const bool ok = col < DD;
    const int colc = ok ? col : 0;
    const float* p0 = &X[(size_t)(bm + r0) * DD + colc];
    const float* p1 = &X[(size_t)(bm + r0 + 64) * DD + colc];
    d[0] = *(const float4*)p0; d[1] = *(const float4*)(p0 + 4);
    d[2] = *(const float4*)p1; d[3] = *(const float4*)(p1 + 4);
    if (!ok) {
      const float4 z = make_float4(0.f, 0.f, 0.f, 0.f);
      d[0] = z; d[1] = z; d[2] = z; d[3] = z;
    }
  };
  auto packA = [&](int bi, const float4 (&s_)[4]) {
    const unsigned ONE = 0x3C00u;
    auto pk = [&](float a, float b) {
      return (a != 0.f ? ONE : 0u) | (b != 0.f ? (ONE << 16) : 0u);
    };
    uint4 v0, v1;
    v0.x = pk(s_[0].x, s_[0].y); v0.y = pk(s_[0].z, s_[0].w);
    v0.z = pk(s_[1].x, s_[1].y); v0.w = pk(s_[1].z, s_[1].w);
    v1.x = pk(s_[2].x, s_[2].y); v1.y = pk(s_[2].z, s_[2].w);
    v1.z = pk(s_[3].x, s_[3].y); v1.w = pk(s_[3].z, s_[3].w);
    *(uint4*)&Asm[bi][r0 * 32 + c0phys] = v0;
    *(uint4*)&Asm[bi][(r0 + 64) * 32 + c0phys] = v1;
  };
  auto stageB = [&](int t) {
    const int k0 = t * 32, bi = t % 3;
    glds16(bsrc0 + k0, &Bsm[bi][0][(wid * 32) * 32]);
    glds16(bsrc1 + k0, &Bsm[bi][0][(wid * 32 + 16) * 32]);
    glds16(bsrc0 + pstr + k0, &Bsm[bi][1][(wid * 32) * 32]);
    glds16(bsrc1 + pstr + k0, &Bsm[bi][1][(wid * 32 + 16) * 32]);
  };
  auto compute = [&](int kb) {
    const int cb = kb & 1, b3 = kb % 3;
    f16x8 afr[4];
#pragma unroll
    for (int m = 0; m < 4; ++m)
      afr[m] = *(const f16x8*)&Asm[cb][(wr + m * 16 + l15) * 32 + rdsw];
#pragma unroll
    for (int s = 0; s < 2; ++s) {
      f16x8 bfr[4];
#pragma unroll
      for (int n = 0; n < 4; ++n)
        bfr[n] = *(const f16x8*)&Bsm[b3][s][(wc + n * 16 + l15) * 32 + rdsw];
#pragma unroll
      for (int m = 0; m < 4; ++m)
#pragma unroll
        for (int n = 0; n < 4; ++n)
          acc[s][m][n] = __builtin_amdgcn_mfma_f32_16x16x32_f16(afr[m], bfr[n], acc[s][m][n], 0, 0, 0);
    }
  };
  auto stepK = [&](int kb, const float4 (&pk_)[4], float4 (&ld_)[4]) {
    if (kb + 1 < nkb) packA((kb + 1) & 1, pk_);
    if (kb + 2 < nkb) stageB(kb + 2);
    compute(kb);
    __builtin_amdgcn_sched_barrier(0);
    if (kb + 2 < nkb) asm volatile("s_waitcnt vmcnt(4)" ::: "memory");
    else              asm volatile("s_waitcnt vmcnt(0)" ::: "memory");
    if (kb + 2 < nkb) loadA(kb + 2, ld_);
    asm volatile("s_waitcnt lgkmcnt(0)" ::: "memory");
    __builtin_amdgcn_sched_barrier(0);
    __builtin_amdgcn_s_barrier();
    __builtin_amdgcn_sched_barrier(0);
  };

  loadA(0, aA);
  stageB(0); stageB(1);
  asm volatile("s_waitcnt vmcnt(8)" ::: "memory");
  packA(0, aA);
  loadA(1, aB);
  asm volatile("s_waitcnt vmcnt(8)" ::: "memory");
  asm volatile("s_waitcnt lgkmcnt(0)" ::: "memory");
  __builtin_amdgcn_s_barrier();
  __builtin_amdgcn_sched_barrier(0);

  for (int kb2 = 0; kb2 < nkb; kb2 += 2) {
    stepK(kb2, aB, aA);
    if (kb2 + 1 < nkb) stepK(kb2 + 1, aA, aB);
  }

#pragma unroll
  for (int m = 0; m < 4; ++m)
#pragma unroll
    for (int n = 0; n < 4; ++n) {
      const int col = bn + wc + n * 16 + l15;
      const float bv = bias[col];
#pragma unroll
      for (int r = 0; r < 4; ++r) {
        const int row = bm + wr + m * 16 + l4 * 4 + r;
        C[(size_t)row * HH + col] = fmaf(acc[1][m][n][r], INVMID, acc[0][m][n][r]) + bv;
      }
    }
}

// fp32 currents -> f16 spikes, 4 elems/thread
__global__ __launch_bounds__(256)
void lif_scan_h4(const float4* __restrict__ cur, uint2* __restrict__ spk,
                 int NE4, int nt) {
  const int tid = blockIdx.x * 256 + threadIdx.x;
  float4 mem = make_float4(0.f, 0.f, 0.f, 0.f);
  auto step1 = [](float& m, float c) {
    const float reset = (m > 1.0f) ? 1.0f : 0.0f;
    m = __fsub_rn(__fadd_rn(__fmul_rn(0.9f, m), c), reset);
    return (m > 1.0f);
  };
#pragma unroll 4
  for (int t = 0; t < nt; ++t) {
    const float4 c = cur[(size_t)t * NE4 + tid];
    unsigned s0 = step1(mem.x, c.x) ? 0x3C00u : 0u;
    unsigned s1 = step1(mem.y, c.y) ? 0x3C00u : 0u;
    unsigned s2 = step1(mem.z, c.z) ? 0x3C00u : 0u;
    unsigned s3 = step1(mem.w, c.w) ? 0x3C00u : 0u;
    uint2 o;
    o.x = s0 | (s1 << 16);
    o.y = s2 | (s3 << 16);
    spk[(size_t)t * NE4 + tid] = o;
  }
}

// Fused layer-2 v9: producer/consumer wave split. Block = 16b x 16d, 2 waves.
// Wave0 (producer): glds-ring GEMM for all 100 t (pure-glds vmcnt FIFO: stage(t)
// issued at t-2; steady wait vmcnt(16)); combines planes + bias (identical
// expression to r14) and ds_writes cur (f32, [d][b] stride-17 bank-spread) into
// a 2-chunk x 10-t ring. Wave1 (consumer): a chunk behind, LIF + global stores
// (identical ops). 10 matched s_barriers/wave. LDS 24+21.8 = 45.8 KB ->
// 3 blocks/CU; 784 blocks x 2 waves = 1.53 waves/SIMD (2x r14).
__global__ __launch_bounds__(128)
void fused_l2(const unsigned short* __restrict__ spk1,   // [100][256][256] f16
              const unsigned short* __restrict__ W2s,    // 2 planes [800][256] f16
              const float* __restrict__ b2, float* __restrict__ out) {
  constexpr int CT = 10;                          // t-chunk (100 = 10*10)
  __shared__ unsigned short Aring[3][16 * 256];   // 24 KB
  __shared__ float curb[2][CT][16 * 17];          // 21.76 KB, [d][b] stride 17
  const int tid = threadIdx.x, wid = tid >> 6, lane = tid & 63;
  const int l15 = lane & 15, l4 = lane >> 4;
  const int bb = blockIdx.x / 49, dd = blockIdx.x - bb * 49;  // 16 x 49
  const int b0 = bb * 16, d0 = dd * 16;

  if (wid == 0) {
    // ---------------- producer: GEMM -> cur LDS ----------------
    const unsigned short* asrc[8];
#pragma unroll
    for (int i = 0; i < 8; ++i) {
      const int r = 2 * i + (lane >> 5);
      const int e = ((lane & 31) * 8) ^ ((r & 7) << 3);
      asrc[i] = spk1 + (size_t)(b0 + r) * HH + e;
    }
    auto stageA = [&](int t) {
      const size_t toff = (size_t)t * (BB * HH);
      unsigned short* dst = &Aring[t % 3][0];
#pragma unroll
      for (int i = 0; i < 8; ++i)
        glds16(asrc[i] + toff, dst + 2 * i * 256);
    };

    stageA(0);
    stageA(1);

    f16x8 wfr[2][8];
    const unsigned short* wb = W2s + (size_t)(d0 + l15) * HH + l4 * 8;
#pragma unroll
    for (int s = 0; s < 2; ++s)
#pragma unroll
      for (int ks = 0; ks < 8; ++ks)
        wfr[s][ks] = *(const f16x8*)(wb + (size_t)s * (N2PAD * HH) + ks * 32);
    const float bv = b2[d0 + l15];

    // drain wfr/bv (and stage(0),(1) happen to land too early — acceptable once)
    asm volatile("s_waitcnt vmcnt(0)" ::: "memory");
    __builtin_amdgcn_sched_barrier(0);
    stageA(0 + 2 - 2);  // no-op placeholder removed by constant folding? keep simple:
    // (stage(0),(1) were drained above; re-derive FIFO from empty queue)

    int roff[8];
#pragma unroll
    for (int ks = 0; ks < 8; ++ks)
      roff[ks] = l15 * 256 + ((ks * 32 + l4 * 8) ^ ((l15 & 7) << 3));

    for (int t = 0; t < TT; ++t) {
      if (t + 2 < TT) stageA(t + 2);
      // FIFO (empty at loop entry; stage(t) issued at t-2):
      //   newer than stage(t): stage(t+1), stage(t+2) = 16 -> vmcnt(16);
      //   t=98: only stage(99) newer -> 8; t=99: 0.
      if (t + 2 < TT)      asm volatile("s_waitcnt vmcnt(16)" ::: "memory");
      else if (t + 1 < TT) asm volatile("s_waitcnt vmcnt(8)"  ::: "memory");
      else                 asm volatile("s_waitcnt vmcnt(0)"  ::: "memory");
      __builtin_amdgcn_sched_barrier(0);

      const unsigned short* abuf = &Aring[t % 3][0];
      f16x8 rA[8];
#pragma unroll
      for (int ks = 0; ks < 8; ++ks)
        rA[ks] = *(const f16x8*)&abuf[roff[ks]];
      f32x4 p0a = (f32x4){0.f, 0.f, 0.f, 0.f}, p0b = p0a, p1a = p0a, p1b = p0a;
#pragma unroll
      for (int ks = 0; ks < 4; ++ks) {
        p0a = __builtin_amdgcn_mfma_f32_16x16x32_f16(rA[ks], wfr[0][ks], p0a, 0, 0, 0);
        p1a = __builtin_amdgcn_mfma_f32_16x16x32_f16(rA[ks], wfr[1][ks], p1a, 0, 0, 0);
      }
#pragma unroll
      for (int ks = 4; ks < 8; ++ks) {
        p0b = __builtin_amdgcn_mfma_f32_16x16x32_f16(rA[ks], wfr[0][ks], p0b, 0, 0, 0);
        p1b = __builtin_amdgcn_mfma_f32_16x16x32_f16(rA[ks], wfr[1][ks], p1b, 0, 0, 0);
      }
      // combine (identical expression to r14) and write cur[d=l15][b=l4*4+r]
      float4 cv;
      cv.x = fmaf(p1a[0] + p1b[0], INVMID, p0a[0] + p0b[0]) + bv;
      cv.y = fmaf(p1a[1] + p1b[1], INVMID, p0a[1] + p0b[1]) + bv;
      cv.z = fmaf(p1a[2] + p1b[2], INVMID, p0a[2] + p0b[2]) + bv;
      cv.w = fmaf(p1a[3] + p1b[3], INVMID, p0a[3] + p0b[3]) + bv;
      *(float4*)&curb[(t / CT) & 1][t % CT][l15 * 17 + l4 * 4] = cv;

      if (t % CT == CT - 1) {          // chunk complete
        asm volatile("s_waitcnt lgkmcnt(0)" ::: "memory");
        __builtin_amdgcn_sched_barrier(0);
        __builtin_amdgcn_s_barrier();
      }
    }
  } else {
    // ---------------- consumer: LIF + stores, one chunk behind ----------------
    const int cd = lane & 15, cb4 = lane >> 4;   // d-col, b-quad
    float* obase = out + (size_t)(b0 + cb4 * 4) * DD + d0 + cd;
    float mem0 = 0.f, mem1 = 0.f, mem2 = 0.f, mem3 = 0.f;
    auto lif1 = [](float& m, float c) {
      const float reset = (m > 1.0f) ? 1.0f : 0.0f;
      m = __fsub_rn(__fadd_rn(__fmul_rn(0.9f, m), c), reset);
      return (m > 1.0f) ? 1.0f : 0.0f;
    };
    for (int c = 0; c < TT / CT; ++c) {
      __builtin_amdgcn_s_barrier();              // producer finished chunk c
#pragma unroll
      for (int j = 0; j < CT; ++j) {
        const float4 cv = *(const float4*)&curb[c & 1][j][cd * 17 + cb4 * 4];
        float* op = obase + (size_t)(c * CT + j) * ((size_t)BB * DD);
        op[0]            = lif1(mem0, cv.x);
        op[(size_t)DD]   = lif1(mem1, cv.y);
        op[(size_t)2*DD] = lif1(mem2, cv.z);
        op[(size_t)3*DD] = lif1(mem3, cv.w);
      }
    }
  }
}

extern "C" void kernel_launch(void* const* d_in, const int* in_sizes, int n_in,
                              void* d_out, int out_size, void* d_ws, size_t ws_size,
                              hipStream_t stream) {
  const float* x  = (const float*)d_in[0];
  const float* W1 = (const float*)d_in[1];
  const float* b1 = (const float*)d_in[2];
  const float* W2 = (const float*)d_in[3];
  const float* b2 = (const float*)d_in[4];
  float* out = (float*)d_out;

  const size_t w1s_elems = (size_t)2 * HH * K1PAD;    // 409600
  const size_t w2s_elems = (size_t)2 * N2PAD * HH;    // 409600
  unsigned short* W1s = (unsigned short*)d_ws;
  unsigned short* W2s = W1s + w1s_elems;
  float* cur1 = (float*)(W2s + w2s_elems);
  unsigned short* spk1 = (unsigned short*)(cur1 + (size_t)MM * HH);

  dim3 blk(256);

  split_w<<<dim3((HH * K1PAD + 255) / 256), blk, 0, stream>>>(W1, W1s, HH, DD, HH, K1PAD);
  split_w<<<dim3((N2PAD * HH + 255) / 256), blk, 0, stream>>>(W2, W2s, DD, HH, N2PAD, HH);

  // layer 1: cur1[M,256] = X @ W1^T + b1 (r12 config: 400 blocks x 4 waves)
  gemm1<<<dim3(MM / 128, HH / 128), blk, 0, stream>>>(x, W1s, b1, cur1);

  // layer 1 LIF -> f16 spikes
  lif_scan_h4<<<dim3((BB * HH / 4) / 256), blk, 0, stream>>>(
      (const float4*)cur1, (uint2*)spk1, BB * HH / 4, TT);

  // layer 2: producer/consumer fused, 784 blocks x 2 waves
  fused_l2<<<dim3(16 * 49), dim3(128), 0, stream>>>(spk1, W2s, b2, out);
}